// Round 7
// baseline (67.391 us; speedup 1.0000x reference)
//
#include <hip/hip_runtime.h>
#include <math.h>

typedef unsigned short ushort;
typedef unsigned int uint;
typedef unsigned char uchar;

#define B 4
#define C 64
#define H 64
#define W 64
#define HW 4096
#define NEG 256
#define CHUNK_P 8
#define NCHUNK (HW / CHUNK_P)   // 512
#define NGRP 16
#define CHPG (NCHUNK / NGRP)    // 32 chunks feed each partial2 group

#define INV127SQ 6.20014733e-5f  // 1/(127*127)

// ---------------- ws layout (float units) ----------------
// z2i8   : [B][HW][64] i8 (column pre-normalized, x127) = B*HW*16 floats
// n1map  : [B][HW]
// imgt4  : [HW][4]
// partial2:[B][NGRP][NEG]  (atomically accumulated)
#define OFF_Z2T     0
#define OFF_N1MAP   (OFF_Z2T + B*HW*16)
#define OFF_IMGT4   (OFF_N1MAP + B*HW)
#define OFF_PART2   (OFF_IMGT4 + HW*4)

__device__ __forceinline__ int dot4(uint a, uint b, int c) {
#if __has_builtin(__builtin_amdgcn_sdot4)
    return __builtin_amdgcn_sdot4((int)a, (int)b, c, false);
#else
    return c + (int)(char)(a)       * (int)(char)(b)
             + (int)(char)(a >> 8)  * (int)(char)(b >> 8)
             + (int)(char)(a >> 16) * (int)(char)(b >> 16)
             + (int)(char)(a >> 24) * (int)(char)(b >> 24);
#endif
}

// quad_perm DPP cross-lane int adds (within 4-lane group); VALU, no DS pipe.
__device__ __forceinline__ int dpp_swap1(int x) {
#if __has_builtin(__builtin_amdgcn_update_dpp)
    return __builtin_amdgcn_update_dpp(0, x, 0xB1, 0xF, 0xF, true);
#else
    return __shfl_xor(x, 1);
#endif
}
__device__ __forceinline__ int dpp_swap2(int x) {
#if __has_builtin(__builtin_amdgcn_update_dpp)
    return __builtin_amdgcn_update_dpp(0, x, 0x4E, 0xF, 0xF, true);
#else
    return __shfl_xor(x, 2);
#endif
}

__device__ __forceinline__ uint pack4i8(float a, float b, float c, float d) {
    int i0 = (int)rintf(a), i1 = (int)rintf(b), i2 = (int)rintf(c), i3 = (int)rintf(d);
    return (uint)(i0 & 0xff) | ((uint)(i1 & 0xff) << 8) |
           ((uint)(i2 & 0xff) << 16) | ((uint)(i3 & 0xff) << 24);
}

// Transpose views_2 (C,HW) -> z2i8 (HW,C) int8, columns pre-divided by norm, x127.
__global__ __launch_bounds__(256) void k_prep_z2(const float* __restrict__ v2,
                                                 uchar* __restrict__ z2i8) {
    __shared__ float tile[64][65];
    __shared__ float npart[4][64];
    __shared__ float ninv[64];
    int b  = blockIdx.x >> 6;
    int q0 = (blockIdx.x & 63) * 64;
    int t  = threadIdx.x;
    int qq = t & 63;
    int cg = t >> 6;
    const float* src = v2 + (size_t)b * C * HW;
    float acc = 0.f;
#pragma unroll
    for (int r = 0; r < 16; ++r) {
        int c = cg * 16 + r;
        float v = src[(size_t)c * HW + q0 + qq];
        tile[c][qq] = v;
        acc += v * v;
    }
    npart[cg][qq] = acc;
    __syncthreads();
    if (t < 64) {
        float s = npart[0][t] + npart[1][t] + npart[2][t] + npart[3][t];
        ninv[t] = 127.0f / fmaxf(sqrtf(s), 1e-8f);
    }
    __syncthreads();
    int qw = t >> 2;
    int c0 = (t & 3) * 16;
    float inv = ninv[qw];
    uint us[4];
#pragma unroll
    for (int j = 0; j < 4; ++j)
        us[j] = pack4i8(tile[c0 + 4*j][qw] * inv, tile[c0 + 4*j + 1][qw] * inv,
                        tile[c0 + 4*j + 2][qw] * inv, tile[c0 + 4*j + 3][qw] * inv);
    uint4* dst = (uint4*)(z2i8 + ((size_t)(b * HW + q0 + qw)) * 64 + c0);
    *dst = make_uint4(us[0], us[1], us[2], us[3]);
}

// n1map (per-pixel norm of views_1) + img as float4 table.
__global__ __launch_bounds__(256) void k_prep_z1(const float* __restrict__ v1,
                                                 const float* __restrict__ img,
                                                 float* __restrict__ n1map,
                                                 float* __restrict__ imgt4) {
    int b = blockIdx.x >> 4;
    int q = (blockIdx.x & 15) * 256 + threadIdx.x;
    const float* src = v1 + (size_t)b * C * HW + q;
    float acc = 0.f;
#pragma unroll 8
    for (int c = 0; c < C; ++c) {
        float v = src[(size_t)c * HW];
        acc += v * v;
    }
    n1map[b * HW + q] = sqrtf(acc);
    if (b == 0) {
        float4 ip = make_float4(img[q], img[HW + q], img[2 * HW + q], 0.f);
        *(float4*)(imgt4 + q * 4) = ip;
    }
}

// Main: block = (b, 8 pixels). Phase A: q/w per (pp,k) into LDS (t=k).
// Phase B: 4-lane cooperative i8 column gather (ONE 64B line per column),
// v_dot4_i32_i8, DPP int reduce, atomic accumulate into partial2.
__global__ __launch_bounds__(256) void k_main(const float* __restrict__ v1,
                                              const int* __restrict__ negh,
                                              const int* __restrict__ negw,
                                              const uchar* __restrict__ z2i8,
                                              const float* __restrict__ n1map,
                                              const float* __restrict__ imgt4,
                                              float* __restrict__ partial2) {
    __shared__ __align__(16) uint z1q[CHUNK_P][16];    // i8-packed z1 columns
    __shared__ ushort q_lds[CHUNK_P][NEG];
    __shared__ float  w_lds[CHUNK_P][NEG];             // weight * 1/127^2
    __shared__ float4 imgps[CHUNK_P];
    int b     = blockIdx.x >> 9;       // NCHUNK = 512
    int chunk = blockIdx.x & 511;
    int p0    = chunk * CHUNK_P;
    int t     = threadIdx.x;

    if (t < 128) {   // stage z1 columns, normalized x127 -> i8 packed
        int pp = t & 7;
        int cu = t >> 3;               // 0..15, channels 4cu..4cu+3
        const float* srcb = v1 + (size_t)b * C * HW + p0 + pp;
        float inv = 127.0f / fmaxf(n1map[b * HW + p0 + pp], 1e-8f);
        float a0 = srcb[(size_t)(4 * cu)     * HW] * inv;
        float a1 = srcb[(size_t)(4 * cu + 1) * HW] * inv;
        float a2 = srcb[(size_t)(4 * cu + 2) * HW] * inv;
        float a3 = srcb[(size_t)(4 * cu + 3) * HW] * inv;
        z1q[pp][cu] = pack4i8(a0, a1, a2, a3);
    }
    if (t < CHUNK_P) imgps[t] = *(const float4*)(imgt4 + (p0 + t) * 4);
    __syncthreads();

    const float inv_max_euc = 1.0f / sqrtf((float)((H - 1) * (H - 1) + (W - 1) * (W - 1)));
    const float inv_sqrt3   = 0.57735026919f;
    const int* nh = negh + ((size_t)b * HW + p0) * NEG + t;
    const int* nw = negw + ((size_t)b * HW + p0) * NEG + t;

    // Phase A: thread t = k index
#pragma unroll
    for (int pp = 0; pp < CHUNK_P; ++pp) {
        int p = p0 + pp;
        int ih = nh[pp * NEG];
        int iw = nw[pp * NEG];
        int qv = (ih << 6) + iw;
        float dh = (float)(p >> 6) - (float)ih;
        float dw = (float)(p & 63) - (float)iw;
        float euc = sqrtf(dh * dh + dw * dw) * inv_max_euc;
        float4 iq = *(const float4*)(imgt4 + qv * 4);
        float4 ip = imgps[pp];
        float dr = ip.x - iq.x, dg = ip.y - iq.y, db = ip.z - iq.z;
        float rgb = sqrtf(dr * dr + dg * dg + db * db) * inv_sqrt3;
        q_lds[pp][t] = (ushort)qv;
        w_lds[pp][t] = (0.8f * euc + 0.2f * rgb) * INV127SQ;
    }
    __syncthreads();

    // Phase B: 4 lanes per column; column = one 64B line.
    int c4 = t & 3;
    int kk = t >> 2;                   // 0..63 across block
    const uchar* z2b = z2i8 + (size_t)b * HW * 64;
    float acc = 0.f;
#pragma unroll 1
    for (int pp = 0; pp < CHUNK_P; ++pp) {
        const uint4* z1a = (const uint4*)(&z1q[pp][0]);
        uint4 ua = z1a[c4];            // channels 16c4 .. 16c4+15
#pragma unroll
        for (int g = 0; g < 4; ++g) {
            int kq = (g << 6) + kk;
            int qv = q_lds[pp][kq];
            float wv = w_lds[pp][kq];
            const uint4* col = (const uint4*)(z2b + (size_t)qv * 64);
            uint4 A = col[c4];         // 16 B = 16 channels
            int di = 0;
            di = dot4(A.x, ua.x, di);
            di = dot4(A.y, ua.y, di);
            di = dot4(A.z, ua.z, di);
            di = dot4(A.w, ua.w, di);
            di += dpp_swap1(di);
            di += dpp_swap2(di);
            float s = fminf(fabsf((float)di * wv), 1.0f);
            acc += (g == c4) ? s : 0.f;
        }
    }
    atomicAdd(&partial2[(((size_t)b * NGRP) + (chunk >> 5)) * NEG + (c4 << 6) + kk], acc);
}

// Merged stage-2 + final: one block handles all 4 items and writes the 3 outputs.
__global__ __launch_bounds__(256) void k_reduce2f(const float* __restrict__ partial2,
                                                  const float* __restrict__ n1map,
                                                  float* __restrict__ out) {
    __shared__ float red[256];
    int t = threadIdx.x;
    float bsum = 0.f, s0sum = 0.f, snegsum = 0.f;
    for (int b = 0; b < B; ++b) {
        float s = 0.f;
#pragma unroll
        for (int g = 0; g < NGRP; ++g)
            s += partial2[((size_t)b * NGRP + g) * NEG + t];
        float sneg = s * (1.0f / HW) * 0.5f;               // / HW / TEMPERATURE
        float l1m  = fmaxf(logf(1.0f - sneg), -100.0f);
        float ss = 0.f;
#pragma unroll
        for (int j = 0; j < HW / 256; ++j) {
            float n1 = n1map[b * HW + j * 256 + t];
            float n1sq = n1 * n1;
            ss += fminf(n1sq / fmaxf(n1sq, 1e-8f), 1.0f);
        }
        float snegsum_b, l1msum_b, sssum_b;
        red[t] = sneg; __syncthreads();
        for (int sft = 128; sft > 0; sft >>= 1) { if (t < sft) red[t] += red[t + sft]; __syncthreads(); }
        snegsum_b = red[0]; __syncthreads();
        red[t] = l1m; __syncthreads();
        for (int sft = 128; sft > 0; sft >>= 1) { if (t < sft) red[t] += red[t + sft]; __syncthreads(); }
        l1msum_b = red[0]; __syncthreads();
        red[t] = ss; __syncthreads();
        for (int sft = 128; sft > 0; sft >>= 1) { if (t < sft) red[t] += red[t + sft]; __syncthreads(); }
        sssum_b = red[0]; __syncthreads();
        float s0  = sssum_b * (1.0f / HW);
        float bce = -(fmaxf(logf(s0), -100.0f) + l1msum_b) * (1.0f / (NEG + 1));
        bsum    += bce;
        s0sum   += s0;
        snegsum += snegsum_b;
    }
    if (t == 0) {
        out[0] = bsum * 0.25f;                              // mean bce
        out[1] = s0sum * 0.25f;                             // sim_all[0] / B
        out[2] = snegsum * (1.0f / NEG) * 2.0f * 0.25f;     // sum/NEG*TEMP/B
    }
}

extern "C" void kernel_launch(void* const* d_in, const int* in_sizes, int n_in,
                              void* d_out, int out_size, void* d_ws, size_t ws_size,
                              hipStream_t stream) {
    const float* v1   = (const float*)d_in[0];
    const float* v2   = (const float*)d_in[1];
    const float* img  = (const float*)d_in[2];
    const int*   negh = (const int*)d_in[3];
    const int*   negw = (const int*)d_in[4];
    float* out = (float*)d_out;
    float* ws  = (float*)d_ws;

    uchar* z2i8     = (uchar*)(ws + OFF_Z2T);
    float* n1map    = ws + OFF_N1MAP;
    float* imgt4    = ws + OFF_IMGT4;
    float* partial2 = ws + OFF_PART2;

    hipMemsetAsync(partial2, 0, (size_t)B * NGRP * NEG * sizeof(float), stream);
    hipLaunchKernelGGL(k_prep_z2, dim3(B * 64), dim3(256), 0, stream, v2, z2i8);
    hipLaunchKernelGGL(k_prep_z1, dim3(B * 16), dim3(256), 0, stream, v1, img, n1map, imgt4);
    hipLaunchKernelGGL(k_main, dim3(B * NCHUNK), dim3(256), 0, stream,
                       v1, negh, negw, z2i8, n1map, imgt4, partial2);
    hipLaunchKernelGGL(k_reduce2f, dim3(1), dim3(256), 0, stream, partial2, n1map, out);
}

// Round 8
// 55.684 us; speedup vs baseline: 1.2102x; 1.2102x over previous
//
#include <hip/hip_runtime.h>
#include <math.h>

typedef unsigned short ushort;
typedef unsigned int uint;
typedef unsigned char uchar;

#define B 4
#define C 64
#define H 64
#define W 64
#define HW 4096
#define NEG 256
#define CHUNK_P 8
#define NCHUNK (HW / CHUNK_P)   // 512
#define NGRP 16

#define INV127SQ 6.20014733e-5f  // 1/(127*127)
#define RGBNORM  2.26410874e-3f  // 1/(255*sqrt(3))

// ---------------- ws layout (float units) ----------------
// z2i8   : [B][HW][64] i8 (column pre-normalized, x127) = B*HW*16 floats
// n1map  : [B][HW]
// imgu8  : [HW] uint (packed u8 r,g,b)
// partial2:[B][NGRP][NEG]  (atomically accumulated; zeroed by k_prep_z1)
#define OFF_Z2T     0
#define OFF_N1MAP   (OFF_Z2T + B*HW*16)
#define OFF_IMGU8   (OFF_N1MAP + B*HW)
#define OFF_PART2   (OFF_IMGU8 + HW)

__device__ __forceinline__ int dot4(uint a, uint b, int c) {
#if __has_builtin(__builtin_amdgcn_sdot4)
    return __builtin_amdgcn_sdot4((int)a, (int)b, c, false);
#else
    return c + (int)(char)(a)       * (int)(char)(b)
             + (int)(char)(a >> 8)  * (int)(char)(b >> 8)
             + (int)(char)(a >> 16) * (int)(char)(b >> 16)
             + (int)(char)(a >> 24) * (int)(char)(b >> 24);
#endif
}

__device__ __forceinline__ int dpp_swap1(int x) {
#if __has_builtin(__builtin_amdgcn_update_dpp)
    return __builtin_amdgcn_update_dpp(0, x, 0xB1, 0xF, 0xF, true);
#else
    return __shfl_xor(x, 1);
#endif
}
__device__ __forceinline__ int dpp_swap2(int x) {
#if __has_builtin(__builtin_amdgcn_update_dpp)
    return __builtin_amdgcn_update_dpp(0, x, 0x4E, 0xF, 0xF, true);
#else
    return __shfl_xor(x, 2);
#endif
}

__device__ __forceinline__ uint pack4i8(float a, float b, float c, float d) {
    int i0 = (int)rintf(a), i1 = (int)rintf(b), i2 = (int)rintf(c), i3 = (int)rintf(d);
    return (uint)(i0 & 0xff) | ((uint)(i1 & 0xff) << 8) |
           ((uint)(i2 & 0xff) << 16) | ((uint)(i3 & 0xff) << 24);
}

// Transpose views_2 (C,HW) -> z2i8 (HW,C) int8, columns pre-divided by norm, x127.
__global__ __launch_bounds__(256) void k_prep_z2(const float* __restrict__ v2,
                                                 uchar* __restrict__ z2i8) {
    __shared__ float tile[64][65];
    __shared__ float npart[4][64];
    __shared__ float ninv[64];
    int b  = blockIdx.x >> 6;
    int q0 = (blockIdx.x & 63) * 64;
    int t  = threadIdx.x;
    int qq = t & 63;
    int cg = t >> 6;
    const float* src = v2 + (size_t)b * C * HW;
    float acc = 0.f;
#pragma unroll
    for (int r = 0; r < 16; ++r) {
        int c = cg * 16 + r;
        float v = src[(size_t)c * HW + q0 + qq];
        tile[c][qq] = v;
        acc += v * v;
    }
    npart[cg][qq] = acc;
    __syncthreads();
    if (t < 64) {
        float s = npart[0][t] + npart[1][t] + npart[2][t] + npart[3][t];
        ninv[t] = 127.0f / fmaxf(sqrtf(s), 1e-8f);
    }
    __syncthreads();
    int qw = t >> 2;
    int c0 = (t & 3) * 16;
    float inv = ninv[qw];
    uint us[4];
#pragma unroll
    for (int j = 0; j < 4; ++j)
        us[j] = pack4i8(tile[c0 + 4*j][qw] * inv, tile[c0 + 4*j + 1][qw] * inv,
                        tile[c0 + 4*j + 2][qw] * inv, tile[c0 + 4*j + 3][qw] * inv);
    uint4* dst = (uint4*)(z2i8 + ((size_t)(b * HW + q0 + qw)) * 64 + c0);
    *dst = make_uint4(us[0], us[1], us[2], us[3]);
}

// n1map + img as packed-u8 table + zero partial2 (grid 64x256 == 16384 entries).
__global__ __launch_bounds__(256) void k_prep_z1(const float* __restrict__ v1,
                                                 const float* __restrict__ img,
                                                 float* __restrict__ n1map,
                                                 uint* __restrict__ img_u8,
                                                 float* __restrict__ partial2) {
    int t = threadIdx.x;
    int b = blockIdx.x >> 4;
    int q = (blockIdx.x & 15) * 256 + t;
    partial2[blockIdx.x * 256 + t] = 0.f;
    const float* src = v1 + (size_t)b * C * HW + q;
    float acc = 0.f;
#pragma unroll 8
    for (int c = 0; c < C; ++c) {
        float v = src[(size_t)c * HW];
        acc += v * v;
    }
    n1map[b * HW + q] = sqrtf(acc);
    if (b == 0) {
        uint r  = (uint)rintf(img[q] * 255.f);
        uint g  = (uint)rintf(img[HW + q] * 255.f);
        uint bl = (uint)rintf(img[2 * HW + q] * 255.f);
        img_u8[q] = r | (g << 8) | (bl << 16);
    }
}

// Main: block = (b, 8 pixels). img table lives in LDS (no scattered global img gather).
// Phase A: {q, f16 w} packed per (pp,k) into LDS (t=k). Phase B: 4-lane cooperative
// i8 column gather (one 64B line/column), v_dot4_i32_i8, DPP reduce, atomic accum.
__global__ __launch_bounds__(256) void k_main(const float* __restrict__ v1,
                                              const int* __restrict__ negh,
                                              const int* __restrict__ negw,
                                              const uchar* __restrict__ z2i8,
                                              const float* __restrict__ n1map,
                                              const uint* __restrict__ img_u8,
                                              float* __restrict__ partial2) {
    __shared__ __align__(16) uint z1q[CHUNK_P][16];    // i8-packed z1 columns
    __shared__ uint qw_lds[CHUNK_P][NEG];              // lo16 = q, hi16 = f16 weight
    __shared__ uint imgu[HW];                          // 16 KB packed u8 RGB
    int b     = blockIdx.x >> 9;       // NCHUNK = 512
    int chunk = blockIdx.x & 511;
    int p0    = chunk * CHUNK_P;
    int t     = threadIdx.x;

    {   // preload whole img table, coalesced
        uint4* d4 = (uint4*)imgu;
        const uint4* s4 = (const uint4*)img_u8;
#pragma unroll
        for (int j = 0; j < 4; ++j) d4[j * 256 + t] = s4[j * 256 + t];
    }
    if (t < 128) {   // stage z1 columns, normalized x127 -> i8 packed
        int pp = t & 7;
        int cu = t >> 3;               // 0..15, channels 4cu..4cu+3
        const float* srcb = v1 + (size_t)b * C * HW + p0 + pp;
        float inv = 127.0f / fmaxf(n1map[b * HW + p0 + pp], 1e-8f);
        float a0 = srcb[(size_t)(4 * cu)     * HW] * inv;
        float a1 = srcb[(size_t)(4 * cu + 1) * HW] * inv;
        float a2 = srcb[(size_t)(4 * cu + 2) * HW] * inv;
        float a3 = srcb[(size_t)(4 * cu + 3) * HW] * inv;
        z1q[pp][cu] = pack4i8(a0, a1, a2, a3);
    }
    __syncthreads();

    const float inv_max_euc = 1.0f / sqrtf((float)((H - 1) * (H - 1) + (W - 1) * (W - 1)));
    const int* nh = negh + ((size_t)b * HW + p0) * NEG + t;
    const int* nw = negw + ((size_t)b * HW + p0) * NEG + t;

    // Phase A: thread t = k index; all img lookups hit LDS.
#pragma unroll
    for (int pp = 0; pp < CHUNK_P; ++pp) {
        int p = p0 + pp;
        int ih = nh[pp * NEG];
        int iw = nw[pp * NEG];
        int qv = (ih << 6) + iw;
        float dh = (float)(p >> 6) - (float)ih;
        float dw = (float)(p & 63) - (float)iw;
        float euc = sqrtf(dh * dh + dw * dw) * inv_max_euc;
        uint up = imgu[p];
        uint uq = imgu[qv];
        int dr = (int)(up & 255u)         - (int)(uq & 255u);
        int dg = (int)((up >> 8) & 255u)  - (int)((uq >> 8) & 255u);
        int db = (int)((up >> 16) & 255u) - (int)((uq >> 16) & 255u);
        float rgb = sqrtf((float)(dr * dr + dg * dg + db * db)) * RGBNORM;
        float wv = 0.8f * euc + 0.2f * rgb;
        ushort hb = __builtin_bit_cast(ushort, (_Float16)wv);
        qw_lds[pp][t] = (uint)qv | ((uint)hb << 16);
    }
    __syncthreads();

    // Phase B: 4 lanes per column; column = one 64B line.
    int c4 = t & 3;
    int kk = t >> 2;                   // 0..15 within wave, 0..63 across block
    const uchar* z2b = z2i8 + (size_t)b * HW * 64;
    float acc = 0.f;
#pragma unroll 1
    for (int pp = 0; pp < CHUNK_P; ++pp) {
        const uint4* z1a = (const uint4*)(&z1q[pp][0]);
        uint4 ua = z1a[c4];            // channels 16c4 .. 16c4+15
#pragma unroll
        for (int g = 0; g < 4; ++g) {
            int kq = (g << 6) + kk;
            uint e = qw_lds[pp][kq];
            uint qv = e & 0xffffu;
            float wv = (float)__builtin_bit_cast(_Float16, (ushort)(e >> 16));
            const uint4* col = (const uint4*)(z2b + (size_t)qv * 64);
            uint4 A = col[c4];         // 16 B = 16 channels
            int di = 0;
            di = dot4(A.x, ua.x, di);
            di = dot4(A.y, ua.y, di);
            di = dot4(A.z, ua.z, di);
            di = dot4(A.w, ua.w, di);
            di += dpp_swap1(di);
            di += dpp_swap2(di);
            float s = fminf(fabsf((float)di * wv) * INV127SQ, 1.0f);
            acc += (g == c4) ? s : 0.f;
        }
    }
    atomicAdd(&partial2[(((size_t)b * NGRP) + (chunk >> 5)) * NEG + (c4 << 6) + kk], acc);
}

// Merged stage-2 + final: one block handles all 4 items and writes the 3 outputs.
__global__ __launch_bounds__(256) void k_reduce2f(const float* __restrict__ partial2,
                                                  const float* __restrict__ n1map,
                                                  float* __restrict__ out) {
    __shared__ float red[256];
    int t = threadIdx.x;
    float bsum = 0.f, s0sum = 0.f, snegsum = 0.f;
    for (int b = 0; b < B; ++b) {
        float s = 0.f;
#pragma unroll
        for (int g = 0; g < NGRP; ++g)
            s += partial2[((size_t)b * NGRP + g) * NEG + t];
        float sneg = s * (1.0f / HW) * 0.5f;               // / HW / TEMPERATURE
        float l1m  = fmaxf(logf(1.0f - sneg), -100.0f);
        float ss = 0.f;
#pragma unroll
        for (int j = 0; j < HW / 256; ++j) {
            float n1 = n1map[b * HW + j * 256 + t];
            float n1sq = n1 * n1;
            ss += fminf(n1sq / fmaxf(n1sq, 1e-8f), 1.0f);
        }
        float snegsum_b, l1msum_b, sssum_b;
        red[t] = sneg; __syncthreads();
        for (int sft = 128; sft > 0; sft >>= 1) { if (t < sft) red[t] += red[t + sft]; __syncthreads(); }
        snegsum_b = red[0]; __syncthreads();
        red[t] = l1m; __syncthreads();
        for (int sft = 128; sft > 0; sft >>= 1) { if (t < sft) red[t] += red[t + sft]; __syncthreads(); }
        l1msum_b = red[0]; __syncthreads();
        red[t] = ss; __syncthreads();
        for (int sft = 128; sft > 0; sft >>= 1) { if (t < sft) red[t] += red[t + sft]; __syncthreads(); }
        sssum_b = red[0]; __syncthreads();
        float s0  = sssum_b * (1.0f / HW);
        float bce = -(fmaxf(logf(s0), -100.0f) + l1msum_b) * (1.0f / (NEG + 1));
        bsum    += bce;
        s0sum   += s0;
        snegsum += snegsum_b;
    }
    if (t == 0) {
        out[0] = bsum * 0.25f;                              // mean bce
        out[1] = s0sum * 0.25f;                             // sim_all[0] / B
        out[2] = snegsum * (1.0f / NEG) * 2.0f * 0.25f;     // sum/NEG*TEMP/B
    }
}

extern "C" void kernel_launch(void* const* d_in, const int* in_sizes, int n_in,
                              void* d_out, int out_size, void* d_ws, size_t ws_size,
                              hipStream_t stream) {
    const float* v1   = (const float*)d_in[0];
    const float* v2   = (const float*)d_in[1];
    const float* img  = (const float*)d_in[2];
    const int*   negh = (const int*)d_in[3];
    const int*   negw = (const int*)d_in[4];
    float* out = (float*)d_out;
    float* ws  = (float*)d_ws;

    uchar* z2i8     = (uchar*)(ws + OFF_Z2T);
    float* n1map    = ws + OFF_N1MAP;
    uint*  img_u8   = (uint*)(ws + OFF_IMGU8);
    float* partial2 = ws + OFF_PART2;

    hipLaunchKernelGGL(k_prep_z2, dim3(B * 64), dim3(256), 0, stream, v2, z2i8);
    hipLaunchKernelGGL(k_prep_z1, dim3(B * 16), dim3(256), 0, stream,
                       v1, img, n1map, img_u8, partial2);
    hipLaunchKernelGGL(k_main, dim3(B * NCHUNK), dim3(256), 0, stream,
                       v1, negh, negw, z2i8, n1map, img_u8, partial2);
    hipLaunchKernelGGL(k_reduce2f, dim3(1), dim3(256), 0, stream, partial2, n1map, out);
}

// Round 9
// 43.546 us; speedup vs baseline: 1.5476x; 1.2787x over previous
//
#include <hip/hip_runtime.h>
#include <math.h>

typedef unsigned short ushort;
typedef unsigned int uint;
typedef unsigned char uchar;

#define B 4
#define C 64
#define H 64
#define W 64
#define HW 4096
#define NEG 256
#define CHUNK_P 8
#define NCHUNK (HW / CHUNK_P)   // 512
#define NGRP 16

#define QS 7.49f
#define INVQS2 (1.0f / (QS * QS))
#define RGBNORM 2.26410874e-3f   // 1/(255*sqrt(3))

// ---------------- ws layout (float units) ----------------
// z2i4   : [B][HW][32B] int4 (column pre-normalized, xQS) = B*HW*8 floats
// n1map  : [B][HW]
// imgu8  : [HW] uint (packed u8 r,g,b)
// partial2:[B][NGRP][NEG]  (atomically accumulated; zeroed by k_prep)
#define OFF_Z2T     0
#define OFF_N1MAP   (OFF_Z2T + B*HW*8)
#define OFF_IMGU8   (OFF_N1MAP + B*HW)
#define OFF_PART2   (OFF_IMGU8 + HW)

__device__ __forceinline__ int nib(uint u, int j) {
    return ((int)(u << (28 - 4 * j))) >> 28;
}
__device__ __forceinline__ int dot8(uint a, uint b, int c) {
#if __has_builtin(__builtin_amdgcn_sdot8)
    return __builtin_amdgcn_sdot8((int)a, (int)b, c, false);
#else
#pragma unroll
    for (int j = 0; j < 8; ++j) c += nib(a, j) * nib(b, j);
    return c;
#endif
}

// Combined prep: blocks [0,256) transpose+quantize z2 -> int4 columns;
// blocks [256,320) do n1map + u8 img table + zero partial2.
__global__ __launch_bounds__(256) void k_prep(const float* __restrict__ v2,
                                              const float* __restrict__ v1,
                                              const float* __restrict__ img,
                                              uchar* __restrict__ z2i4,
                                              float* __restrict__ n1map,
                                              uint* __restrict__ img_u8,
                                              float* __restrict__ partial2) {
    int t = threadIdx.x;
    if (blockIdx.x < 256) {
        __shared__ float tile[64][65];
        __shared__ float npart[4][64];
        __shared__ float ninv[64];
        int b  = blockIdx.x >> 6;
        int q0 = (blockIdx.x & 63) * 64;
        int qq = t & 63;
        int cg = t >> 6;
        const float* src = v2 + (size_t)b * C * HW;
        float acc = 0.f;
#pragma unroll
        for (int r = 0; r < 16; ++r) {
            int c = cg * 16 + r;
            float v = src[(size_t)c * HW + q0 + qq];
            tile[c][qq] = v;
            acc += v * v;
        }
        npart[cg][qq] = acc;
        __syncthreads();
        if (t < 64) {
            float s = npart[0][t] + npart[1][t] + npart[2][t] + npart[3][t];
            ninv[t] = QS / fmaxf(sqrtf(s), 1e-8f);
        }
        __syncthreads();
        int qw = t >> 2;
        int c0 = (t & 3) * 16;
        float inv = ninv[qw];
        uint u0 = 0, u1 = 0;
#pragma unroll
        for (int j = 0; j < 8; ++j) {
            int x0 = (int)rintf(tile[c0 + j][qw] * inv);
            int x1 = (int)rintf(tile[c0 + 8 + j][qw] * inv);
            u0 |= (uint)(x0 & 0xF) << (4 * j);
            u1 |= (uint)(x1 & 0xF) << (4 * j);
        }
        uint2* dst = (uint2*)(z2i4 + ((size_t)(b * HW + q0 + qw)) * 32 + (t & 3) * 8);
        *dst = make_uint2(u0, u1);
    } else {
        int bid = blockIdx.x - 256;          // 0..63
        int b = bid >> 4;
        int q = (bid & 15) * 256 + t;
        partial2[bid * 256 + t] = 0.f;       // 64*256 == B*NGRP*NEG
        const float* src = v1 + (size_t)b * C * HW + q;
        float acc = 0.f;
#pragma unroll 8
        for (int c = 0; c < C; ++c) {
            float v = src[(size_t)c * HW];
            acc += v * v;
        }
        n1map[b * HW + q] = sqrtf(acc);
        if (b == 0) {
            uint r  = (uint)rintf(img[q] * 255.f);
            uint g  = (uint)rintf(img[HW + q] * 255.f);
            uint bl = (uint)rintf(img[2 * HW + q] * 255.f);
            img_u8[q] = r | (g << 8) | (bl << 16);
        }
    }
}

// Main: block = (b, 8 pixels). Phase A: {q, f16 w*INVQS2} into LDS (t=k), img from LDS.
// Phase B: ONE lane per column (k=t), 2x dwordx4 int4 loads, v_dot8_i32_i4.
__global__ __launch_bounds__(256) void k_main(const float* __restrict__ v1,
                                              const int* __restrict__ negh,
                                              const int* __restrict__ negw,
                                              const uchar* __restrict__ z2i4,
                                              const float* __restrict__ n1map,
                                              const uint* __restrict__ img_u8,
                                              float* __restrict__ partial2) {
    __shared__ __align__(16) uint z1q[CHUNK_P][8];     // int4-packed z1 columns (32B each)
    __shared__ uint qw_lds[CHUNK_P][NEG];              // lo16 = q, hi16 = f16 (w*INVQS2)
    __shared__ uint imgu[HW];                          // 16 KB packed u8 RGB
    int b     = blockIdx.x >> 9;       // NCHUNK = 512
    int chunk = blockIdx.x & 511;
    int p0    = chunk * CHUNK_P;
    int t     = threadIdx.x;

    {   // preload whole img table, coalesced
        uint4* d4 = (uint4*)imgu;
        const uint4* s4 = (const uint4*)img_u8;
#pragma unroll
        for (int j = 0; j < 4; ++j) d4[j * 256 + t] = s4[j * 256 + t];
    }
    if (t < 64) {   // stage z1 columns, normalized xQS -> int4 packed
        int pp = t >> 3;
        int ui = t & 7;                // uint index: channels 8ui..8ui+7
        const float* srcb = v1 + (size_t)b * C * HW + p0 + pp;
        float inv = QS / fmaxf(n1map[b * HW + p0 + pp], 1e-8f);
        uint u = 0;
#pragma unroll
        for (int j = 0; j < 8; ++j) {
            int x = (int)rintf(srcb[(size_t)(8 * ui + j) * HW] * inv);
            u |= (uint)(x & 0xF) << (4 * j);
        }
        z1q[pp][ui] = u;
    }
    __syncthreads();

    const float inv_max_euc = 1.0f / sqrtf((float)((H - 1) * (H - 1) + (W - 1) * (W - 1)));
    const int* nh = negh + ((size_t)b * HW + p0) * NEG + t;
    const int* nw = negw + ((size_t)b * HW + p0) * NEG + t;

    // Phase A: thread t = k index; img lookups from LDS.
#pragma unroll
    for (int pp = 0; pp < CHUNK_P; ++pp) {
        int p = p0 + pp;
        int ih = nh[pp * NEG];
        int iw = nw[pp * NEG];
        int qv = (ih << 6) + iw;
        float dh = (float)(p >> 6) - (float)ih;
        float dw = (float)(p & 63) - (float)iw;
        float euc = sqrtf(dh * dh + dw * dw) * inv_max_euc;
        uint up = imgu[p];
        uint uq = imgu[qv];
        int dr = (int)(up & 255u)         - (int)(uq & 255u);
        int dg = (int)((up >> 8) & 255u)  - (int)((uq >> 8) & 255u);
        int db = (int)((up >> 16) & 255u) - (int)((uq >> 16) & 255u);
        float rgb = sqrtf((float)(dr * dr + dg * dg + db * db)) * RGBNORM;
        float wv = (0.8f * euc + 0.2f * rgb) * INVQS2;
        ushort hb = __builtin_bit_cast(ushort, (_Float16)wv);
        qw_lds[pp][t] = (uint)qv | ((uint)hb << 16);
    }
    __syncthreads();

    // Phase B: lane-per-column; hoisted qw reads; 2 scattered dwordx4 per pixel.
    const uchar* z2b = z2i4 + (size_t)b * HW * 32;
    uint e[CHUNK_P];
#pragma unroll
    for (int pp = 0; pp < CHUNK_P; ++pp) e[pp] = qw_lds[pp][t];
    float acc = 0.f;
#pragma unroll 2
    for (int pp = 0; pp < CHUNK_P; ++pp) {
        uint qv = e[pp] & 0xffffu;
        float wv = (float)__builtin_bit_cast(_Float16, (ushort)(e[pp] >> 16));
        const uint4* cp = (const uint4*)(z2b + (size_t)qv * 32);
        uint4 A0 = cp[0];
        uint4 A1 = cp[1];
        const uint4* zc = (const uint4*)(&z1q[pp][0]);   // uniform -> LDS broadcast
        uint4 u0 = zc[0];
        uint4 u1 = zc[1];
        int di = 0;
        di = dot8(A0.x, u0.x, di);
        di = dot8(A0.y, u0.y, di);
        di = dot8(A0.z, u0.z, di);
        di = dot8(A0.w, u0.w, di);
        di = dot8(A1.x, u1.x, di);
        di = dot8(A1.y, u1.y, di);
        di = dot8(A1.z, u1.z, di);
        di = dot8(A1.w, u1.w, di);
        acc += fminf(fabsf((float)di * wv), 1.0f);
    }
    atomicAdd(&partial2[((size_t)b * NGRP + (chunk >> 5)) * NEG + t], acc);
}

// Merged stage-2 + final with shfl wave reductions (8 barriers total).
__global__ __launch_bounds__(256) void k_reduce2f(const float* __restrict__ partial2,
                                                  const float* __restrict__ n1map,
                                                  float* __restrict__ out) {
    __shared__ float xw[3][4];
    int t = threadIdx.x;
    int lane = t & 63;
    int wid  = t >> 6;
    float bsum = 0.f, s0sum = 0.f, snegsum = 0.f;
    for (int b = 0; b < B; ++b) {
        float s = 0.f;
#pragma unroll
        for (int g = 0; g < NGRP; ++g)
            s += partial2[((size_t)b * NGRP + g) * NEG + t];
        float sneg = s * (1.0f / HW) * 0.5f;               // / HW / TEMPERATURE
        float l1m  = fmaxf(logf(1.0f - sneg), -100.0f);
        float ss = 0.f;
#pragma unroll
        for (int j = 0; j < HW / 256; ++j) {
            float n1 = n1map[b * HW + j * 256 + t];
            float n1sq = n1 * n1;
            ss += fminf(n1sq / fmaxf(n1sq, 1e-8f), 1.0f);
        }
        float r0 = sneg, r1 = l1m, r2 = ss;
#pragma unroll
        for (int o = 1; o < 64; o <<= 1) {
            r0 += __shfl_xor(r0, o);
            r1 += __shfl_xor(r1, o);
            r2 += __shfl_xor(r2, o);
        }
        if (lane == 0) { xw[0][wid] = r0; xw[1][wid] = r1; xw[2][wid] = r2; }
        __syncthreads();
        if (t == 0) {
            float sn = xw[0][0] + xw[0][1] + xw[0][2] + xw[0][3];
            float lm = xw[1][0] + xw[1][1] + xw[1][2] + xw[1][3];
            float sv = xw[2][0] + xw[2][1] + xw[2][2] + xw[2][3];
            float s0 = sv * (1.0f / HW);
            bsum    += -(fmaxf(logf(s0), -100.0f) + lm) * (1.0f / (NEG + 1));
            s0sum   += s0;
            snegsum += sn;
        }
        __syncthreads();
    }
    if (t == 0) {
        out[0] = bsum * 0.25f;                              // mean bce
        out[1] = s0sum * 0.25f;                             // sim_all[0] / B
        out[2] = snegsum * (1.0f / NEG) * 2.0f * 0.25f;     // sum/NEG*TEMP/B
    }
}

extern "C" void kernel_launch(void* const* d_in, const int* in_sizes, int n_in,
                              void* d_out, int out_size, void* d_ws, size_t ws_size,
                              hipStream_t stream) {
    const float* v1   = (const float*)d_in[0];
    const float* v2   = (const float*)d_in[1];
    const float* img  = (const float*)d_in[2];
    const int*   negh = (const int*)d_in[3];
    const int*   negw = (const int*)d_in[4];
    float* out = (float*)d_out;
    float* ws  = (float*)d_ws;

    uchar* z2i4     = (uchar*)(ws + OFF_Z2T);
    float* n1map    = ws + OFF_N1MAP;
    uint*  img_u8   = (uint*)(ws + OFF_IMGU8);
    float* partial2 = ws + OFF_PART2;

    hipLaunchKernelGGL(k_prep, dim3(320), dim3(256), 0, stream,
                       v2, v1, img, z2i4, n1map, img_u8, partial2);
    hipLaunchKernelGGL(k_main, dim3(B * NCHUNK), dim3(256), 0, stream,
                       v1, negh, negw, z2i4, n1map, img_u8, partial2);
    hipLaunchKernelGGL(k_reduce2f, dim3(1), dim3(256), 0, stream, partial2, n1map, out);
}